// Round 10
// baseline (288.595 us; speedup 1.0000x reference)
//
#include <hip/hip_runtime.h>
#include <math.h>

#define F 64
#define NPB 160        // nodes per bucket
#define BCAP 3584      // per-bucket capacity in binned (mean 2560, +20 sigma)
#define CHMAX 10240    // max edges per scatter block (LDS stage capacity)

typedef __attribute__((ext_vector_type(8))) short bf16x8;
typedef __attribute__((ext_vector_type(4))) float f32x4;

__device__ inline unsigned short f2bf(float f) {
  unsigned int u = __float_as_uint(f);
  u += 0x7fffu + ((u >> 16) & 1u);   // round-to-nearest-even
  return (unsigned short)(u >> 16);
}

// ---------------- prep: W fragment pack (block 0) + bcnt zero + out init ----------------
__global__ __launch_bounds__(256) void k_prep(const float* __restrict__ W1, const float* __restrict__ W2,
                                              uint4* __restrict__ wf, int* __restrict__ bcnt, int nb,
                                              float* __restrict__ out, const float* __restrict__ bo, int ng) {
  int tid = threadIdx.x;
  if (blockIdx.x == 0) {
    // pack W1/W2 into MFMA B-fragment layout: wf[layer*512 + (c*2+kk)*64 + lane] = 8 bf16 (j=0..7)
    for (int i = tid; i < 1024; i += 256) {
      int layer = i >> 9, rem = i & 511;
      int cb = rem >> 6, lane = rem & 63;
      int c = cb >> 1, kk = cb & 1;
      int l15 = lane & 15, quad = lane >> 4;
      const float* W = layer ? W2 : W1;
      unsigned short p[8];
      #pragma unroll
      for (int j = 0; j < 8; j++) {
        int kd = kk * 32 + quad * 8 + j;
        p[j] = f2bf(W[kd * F + c * 16 + l15]);
      }
      wf[i] = *(const uint4*)p;
    }
  } else {
    for (int i = tid; i < nb * 16; i += 256) bcnt[i] = 0;  // counters padded to 64B lines
    float b0 = bo[0];
    for (int i = tid; i < ng; i += 256) out[i] = b0;
  }
}

// ---------------- MFMA GEMM body: fp32 input rows -> bf16 h + als/ald ----------------
__device__ __forceinline__ void gemm_body(const float* __restrict__ in, const uint4* __restrict__ wf,
                                          const float* __restrict__ avs, const float* __restrict__ avd,
                                          unsigned short* __restrict__ hgb, float* __restrict__ als,
                                          float* __restrict__ ald, int n, int bid, int nbl) {
  int tid = threadIdx.x, lane = tid & 63, wv = tid >> 6;
  int l15 = lane & 15, quad = lane >> 4;
  bf16x8 bfr[4][2];
  #pragma unroll
  for (int cb = 0; cb < 8; cb++) {
    uint4 u = wf[cb * 64 + lane];
    bfr[cb >> 1][cb & 1] = *(const bf16x8*)&u;
  }
  float as_l[4], ad_l[4];
  #pragma unroll
  for (int c = 0; c < 4; c++) { as_l[c] = avs[c * 16 + l15]; ad_l[c] = avd[c * 16 + l15]; }

  int nchunks = n >> 6;
  for (int chunk = bid; chunk < nchunks; chunk += nbl) {
    int r0 = (chunk << 6) + (wv << 4);
    bf16x8 a0, a1;
    const float4* xr = (const float4*)(in + (size_t)(r0 + l15) * F + quad * 8);
    float4 xa = xr[0], xb = xr[1];
    float4 xc = xr[8], xd = xr[9];
    a0[0] = (short)f2bf(xa.x); a0[1] = (short)f2bf(xa.y); a0[2] = (short)f2bf(xa.z); a0[3] = (short)f2bf(xa.w);
    a0[4] = (short)f2bf(xb.x); a0[5] = (short)f2bf(xb.y); a0[6] = (short)f2bf(xb.z); a0[7] = (short)f2bf(xb.w);
    a1[0] = (short)f2bf(xc.x); a1[1] = (short)f2bf(xc.y); a1[2] = (short)f2bf(xc.z); a1[3] = (short)f2bf(xc.w);
    a1[4] = (short)f2bf(xd.x); a1[5] = (short)f2bf(xd.y); a1[6] = (short)f2bf(xd.z); a1[7] = (short)f2bf(xd.w);
    f32x4 cfr[4];
    #pragma unroll
    for (int c = 0; c < 4; c++) {
      cfr[c] = (f32x4){0.f, 0.f, 0.f, 0.f};
      cfr[c] = __builtin_amdgcn_mfma_f32_16x16x32_bf16(a0, bfr[c][0], cfr[c], 0, 0, 0);
      cfr[c] = __builtin_amdgcn_mfma_f32_16x16x32_bf16(a1, bfr[c][1], cfr[c], 0, 0, 0);
    }
    #pragma unroll
    for (int i = 0; i < 4; i++) {
      int row = r0 + quad * 4 + i;
      #pragma unroll
      for (int c = 0; c < 4; c++) hgb[(size_t)row * F + c * 16 + l15] = f2bf(cfr[c][i]);
      float ps = cfr[0][i] * as_l[0] + cfr[1][i] * as_l[1] + cfr[2][i] * as_l[2] + cfr[3][i] * as_l[3];
      float pd = cfr[0][i] * ad_l[0] + cfr[1][i] * ad_l[1] + cfr[2][i] * ad_l[2] + cfr[3][i] * ad_l[3];
      #pragma unroll
      for (int o = 1; o <= 8; o <<= 1) { ps += __shfl_xor(ps, o); pd += __shfl_xor(pd, o); }
      if (l15 == 0) { als[row] = ps; ald[row] = pd; }
    }
  }
}

// ---------------- fused: bucketed scatter w/ LDS counting-sort (blocks < S) + layer-1 GEMM ----
// Scatter block: LDS histogram -> in-block exclusive scan + global run reservation ->
// counting-sort edges into LDS stage -> per-wave COALESCED flush of each bucket run
// (adjacent lanes -> adjacent addresses; each 64B line covered by one wave op).
__global__ __launch_bounds__(256) void k_scatter_gemm1(const int* __restrict__ esrc, const int* __restrict__ edst,
                                                       int* __restrict__ bcnt, unsigned int* __restrict__ binned,
                                                       int e, int ch, int S,
                                                       const float* __restrict__ x, const uint4* __restrict__ wf,
                                                       const float* __restrict__ avs, const float* __restrict__ avd,
                                                       unsigned short* __restrict__ hgb, float* __restrict__ als,
                                                       float* __restrict__ ald, int n) {
  __shared__ int hist[1024];
  __shared__ int lboff[1024];
  __shared__ int gbase[1024];
  __shared__ int scur[1024];
  __shared__ unsigned int stg[CHMAX];
  __shared__ int wsum[4];
  int k = blockIdx.x, tid = threadIdx.x;
  if (k < S) {
    int lane = tid & 63, wv = tid >> 6;
    for (int i = tid; i < 1024; i += 256) hist[i] = 0;
    __syncthreads();
    int beg = k * ch, end = min(e, beg + ch);
    int len = end - beg;
    if (len <= 0) return;
    int nv = len >> 2;  // beg is 16B-aligned (ch multiple of 4)
    // phase A: histogram (int4)
    for (int g = tid; g < nv; g += 256) {
      int4 d4 = *(const int4*)(edst + beg + (g << 2));
      atomicAdd(&hist[d4.x / NPB], 1);
      atomicAdd(&hist[d4.y / NPB], 1);
      atomicAdd(&hist[d4.z / NPB], 1);
      atomicAdd(&hist[d4.w / NPB], 1);
    }
    for (int i = beg + (nv << 2) + tid; i < end; i += 256) atomicAdd(&hist[edst[i] / NPB], 1);
    __syncthreads();
    // phase B1: in-block exclusive scan of hist (4 buckets/thread, wave shfl + cross-wave fixup)
    int b4 = tid * 4;
    int c0 = hist[b4], c1 = hist[b4 + 1], c2 = hist[b4 + 2], c3 = hist[b4 + 3];
    int csum = c0 + c1 + c2 + c3;
    int xs = csum;
    #pragma unroll
    for (int o = 1; o <= 32; o <<= 1) { int y = __shfl_up(xs, o); if (lane >= o) xs += y; }
    if (lane == 63) wsum[wv] = xs;
    __syncthreads();
    int add = 0;
    for (int w = 0; w < wv; w++) add += wsum[w];
    int excl = xs + add - csum;
    lboff[b4] = excl;           scur[b4] = excl;
    lboff[b4 + 1] = excl + c0;  scur[b4 + 1] = excl + c0;
    lboff[b4 + 2] = excl + c0 + c1;       scur[b4 + 2] = excl + c0 + c1;
    lboff[b4 + 3] = excl + c0 + c1 + c2;  scur[b4 + 3] = excl + c0 + c1 + c2;
    // phase B2: reserve per-bucket runs (global atomics on padded counters)
    for (int b = tid; b < 1024; b += 256) {
      int c = hist[b];
      int base = 0;
      if (c) base = atomicAdd(&bcnt[b * 16], c);
      gbase[b] = b * BCAP + base;
    }
    __syncthreads();
    // phase C: counting-sort into LDS stage (LDS atomics only)
    for (int g = tid; g < nv; g += 256) {
      int i = beg + (g << 2);
      int4 d4 = *(const int4*)(edst + i);
      int4 s4 = *(const int4*)(esrc + i);
      #pragma unroll
      for (int j = 0; j < 4; j++) {
        int d = (j == 0) ? d4.x : (j == 1) ? d4.y : (j == 2) ? d4.z : d4.w;
        int s = (j == 0) ? s4.x : (j == 1) ? s4.y : (j == 2) ? s4.z : s4.w;
        int b = d / NPB;
        int p = atomicAdd(&scur[b], 1);
        stg[p] = (unsigned int)s | ((unsigned int)(d - b * NPB) << 24);
      }
    }
    for (int i = beg + (nv << 2) + tid; i < end; i += 256) {
      int d = edst[i];
      int b = d / NPB;
      int p = atomicAdd(&scur[b], 1);
      stg[p] = (unsigned int)esrc[i] | ((unsigned int)(d - b * NPB) << 24);
    }
    __syncthreads();
    // phase D: coalesced flush — wave wv handles buckets wv, wv+4, ...
    for (int b = wv; b < 1024; b += 4) {
      int ln = hist[b];
      int lb = lboff[b];
      int gb = gbase[b];
      int gend = (b + 1) * BCAP;
      for (int t = lane; t < ln; t += 64) {
        int d = gb + t;
        if (d < gend) binned[d] = stg[lb + t];
      }
    }
    return;
  }
  gemm_body(x, wf, avs, avd, hgb, als, ald, n, k - S, (int)gridDim.x - S);
}

// ---------------- fused: per-bucket CSR build + layer-1 aggregation + layer-2 GEMM ----------------
// One block per 160-node bucket. Phases: prefix outbase from bcnt -> LDS counting-sort of the
// bucket's binned run into stage[] (ssrc/offs persisted for spmm_out as a by-product) ->
// aggregate 160 nodes with edge ids from LDS -> layer-2 GEMM on 10 x 16-row strips.
__global__ __launch_bounds__(256) void k_csr_g2(const unsigned int* __restrict__ binned,
                                                const int* __restrict__ bcnt,
                                                int* __restrict__ ssrc, int* __restrict__ offs,
                                                const unsigned short* __restrict__ hgb,
                                                const float* __restrict__ als, const float* __restrict__ ald,
                                                const float* __restrict__ bias, const uint4* __restrict__ wf2,
                                                const float* __restrict__ avs, const float* __restrict__ avd,
                                                unsigned short* __restrict__ hgb2, float* __restrict__ als2,
                                                float* __restrict__ ald2, int n, int nb) {
  __shared__ int ncnt[NPB];
  __shared__ int noff[NPB];
  __shared__ int cur[NPB];
  __shared__ int wsum[4];
  __shared__ int stage[BCAP];
  __shared__ __align__(16) unsigned short hsh[NPB][72];  // stride 144B: 16B-aligned rows, 2-way banks
  int b = blockIdx.x, tid = threadIdx.x;
  int lane = tid & 63, wv = tid >> 6;
  int* red = stage;  // alias: red phase finishes before stage is written (barriers intervene)

  // output base: prefix sum over earlier buckets (bcnt is L2-resident)
  int acc = 0;
  for (int j = tid; j < b; j += 256) acc += min(bcnt[j * 16], BCAP);
  red[tid] = acc;
  __syncthreads();
  #pragma unroll
  for (int o = 128; o > 0; o >>= 1) {
    if (tid < o) red[tid] += red[tid + o];
    __syncthreads();
  }
  int outbase = red[0];
  int ecnt = min(bcnt[b * 16], BCAP);
  int node0 = b * NPB;
  int nn = min(NPB, n - node0);
  const uint4* bq = (const uint4*)(binned + (size_t)b * BCAP);  // BCAP%4==0 -> 16B aligned
  int nv4 = ecnt >> 2;
  for (int i = tid; i < NPB; i += 256) ncnt[i] = 0;
  __syncthreads();
  // hist pass (uint4)
  for (int i = tid; i < nv4; i += 256) {
    uint4 q = bq[i];
    atomicAdd(&ncnt[q.x >> 24], 1);
    atomicAdd(&ncnt[q.y >> 24], 1);
    atomicAdd(&ncnt[q.z >> 24], 1);
    atomicAdd(&ncnt[q.w >> 24], 1);
  }
  for (int i = (nv4 << 2) + tid; i < ecnt; i += 256)
    atomicAdd(&ncnt[binned[(size_t)b * BCAP + i] >> 24], 1);
  __syncthreads();
  // exclusive scan over nn node counts: wave shfl scan + cross-wave fixup
  int v = (tid < nn) ? ncnt[tid] : 0;
  int x = v;
  #pragma unroll
  for (int o = 1; o <= 32; o <<= 1) { int y = __shfl_up(x, o); if (lane >= o) x += y; }
  if (lane == 63) wsum[wv] = x;
  __syncthreads();   // also fences the red->stage alias handoff
  int add = 0;
  for (int w = 0; w < wv; w++) add += wsum[w];
  int incl = x + add;
  if (tid < nn) {
    int nf = incl - v;
    noff[tid] = nf;
    cur[tid] = nf;
    offs[node0 + tid] = outbase + nf;
  }
  __syncthreads();
  // sort pass (uint4) -> stage
  for (int i = tid; i < nv4; i += 256) {
    uint4 q = bq[i];
    int p0 = atomicAdd(&cur[q.x >> 24], 1); stage[p0] = (int)(q.x & 0xFFFFFFu);
    int p1 = atomicAdd(&cur[q.y >> 24], 1); stage[p1] = (int)(q.y & 0xFFFFFFu);
    int p2 = atomicAdd(&cur[q.z >> 24], 1); stage[p2] = (int)(q.z & 0xFFFFFFu);
    int p3 = atomicAdd(&cur[q.w >> 24], 1); stage[p3] = (int)(q.w & 0xFFFFFFu);
  }
  for (int i = (nv4 << 2) + tid; i < ecnt; i += 256) {
    unsigned int q = binned[(size_t)b * BCAP + i];
    int p = atomicAdd(&cur[q >> 24], 1);
    stage[p] = (int)(q & 0xFFFFFFu);
  }
  __syncthreads();
  // persist CSR for spmm_out (coalesced; overlaps with agg below across blocks)
  for (int i = tid; i < ecnt; i += 256) ssrc[outbase + i] = stage[i];
  if (b == nb - 1 && tid == 0) offs[n] = outbase + ecnt;

  // ---- layer-1 aggregation for this bucket's nodes, edge ids from LDS ----
  int g8 = lane >> 3, l8 = lane & 7;
  const uint4* hg4 = (const uint4*)hgb;
  float4 bl0 = ((const float4*)bias)[l8 * 2];
  float4 bl1 = ((const float4*)bias)[l8 * 2 + 1];

  for (int p = 0; p < 5; p++) {
    int row = p * 32 + wv * 8 + g8;       // 0..159
    int node = node0 + row;
    bool rowok = row < nn;
    int cnode = min(node, n - 1);
    int deg = rowok ? ncnt[row] : 0;
    int lbeg = rowok ? noff[row] : 0;
    float aldv = ald[cnode];

    // self-loop term
    float ts = als[cnode] + aldv;
    ts = fmaxf(ts, 0.2f * ts);
    float exs = __expf(ts);
    float s = exs;
    uint4 us = hg4[(size_t)cnode * 8 + l8];
    float acc8[8];
    acc8[0] = exs * __uint_as_float(us.x << 16);
    acc8[1] = exs * __uint_as_float(us.x & 0xffff0000u);
    acc8[2] = exs * __uint_as_float(us.y << 16);
    acc8[3] = exs * __uint_as_float(us.y & 0xffff0000u);
    acc8[4] = exs * __uint_as_float(us.z << 16);
    acc8[5] = exs * __uint_as_float(us.z & 0xffff0000u);
    acc8[6] = exs * __uint_as_float(us.w << 16);
    acc8[7] = exs * __uint_as_float(us.w & 0xffff0000u);

    #pragma unroll 4
    for (int j = 0; j < deg; j++) {
      int src = stage[lbeg + j];
      float t = als[src] + aldv;
      t = fmaxf(t, 0.2f * t);               // leaky_relu 0.2
      float ex = __expf(t);
      s += ex;
      uint4 u = hg4[(size_t)src * 8 + l8];
      acc8[0] = fmaf(ex, __uint_as_float(u.x << 16), acc8[0]);
      acc8[1] = fmaf(ex, __uint_as_float(u.x & 0xffff0000u), acc8[1]);
      acc8[2] = fmaf(ex, __uint_as_float(u.y << 16), acc8[2]);
      acc8[3] = fmaf(ex, __uint_as_float(u.y & 0xffff0000u), acc8[3]);
      acc8[4] = fmaf(ex, __uint_as_float(u.z << 16), acc8[4]);
      acc8[5] = fmaf(ex, __uint_as_float(u.z & 0xffff0000u), acc8[5]);
      acc8[6] = fmaf(ex, __uint_as_float(u.w << 16), acc8[6]);
      acc8[7] = fmaf(ex, __uint_as_float(u.w & 0xffff0000u), acc8[7]);
    }

    float iv = 1.f / (s + 1e-16f);
    float r[8];
    r[0] = fmaxf(fmaf(acc8[0], iv, bl0.x), 0.f);
    r[1] = fmaxf(fmaf(acc8[1], iv, bl0.y), 0.f);
    r[2] = fmaxf(fmaf(acc8[2], iv, bl0.z), 0.f);
    r[3] = fmaxf(fmaf(acc8[3], iv, bl0.w), 0.f);
    r[4] = fmaxf(fmaf(acc8[4], iv, bl1.x), 0.f);
    r[5] = fmaxf(fmaf(acc8[5], iv, bl1.y), 0.f);
    r[6] = fmaxf(fmaf(acc8[6], iv, bl1.z), 0.f);
    r[7] = fmaxf(fmaf(acc8[7], iv, bl1.w), 0.f);
    unsigned short pk[8];
    #pragma unroll
    for (int kk = 0; kk < 8; kk++) pk[kk] = f2bf(r[kk]);
    *(uint4*)&hsh[row][l8 * 8] = *(const uint4*)pk;
  }
  __syncthreads();

  // ---- layer-2 GEMM on 10 strips of 16 rows ----
  int l15 = lane & 15, quad = lane >> 4;
  bf16x8 bfr[4][2];
  #pragma unroll
  for (int cb = 0; cb < 8; cb++) {
    uint4 u = wf2[cb * 64 + lane];
    bfr[cb >> 1][cb & 1] = *(const bf16x8*)&u;
  }
  float as_l[4], ad_l[4];
  #pragma unroll
  for (int c = 0; c < 4; c++) { as_l[c] = avs[c * 16 + l15]; ad_l[c] = avd[c * 16 + l15]; }

  #pragma unroll
  for (int t = 0; t < 3; t++) {
    int strip = t * 4 + wv;
    if (strip < 10) {
      int r0 = strip << 4;
      uint4 u0 = *(const uint4*)&hsh[r0 + l15][quad * 8];
      uint4 u1 = *(const uint4*)&hsh[r0 + l15][quad * 8 + 32];
      bf16x8 a0 = *(const bf16x8*)&u0;
      bf16x8 a1 = *(const bf16x8*)&u1;
      f32x4 cfr[4];
      #pragma unroll
      for (int c = 0; c < 4; c++) {
        cfr[c] = (f32x4){0.f, 0.f, 0.f, 0.f};
        cfr[c] = __builtin_amdgcn_mfma_f32_16x16x32_bf16(a0, bfr[c][0], cfr[c], 0, 0, 0);
        cfr[c] = __builtin_amdgcn_mfma_f32_16x16x32_bf16(a1, bfr[c][1], cfr[c], 0, 0, 0);
      }
      #pragma unroll
      for (int i = 0; i < 4; i++) {
        int row = node0 + r0 + quad * 4 + i;
        if (row < n) {
          #pragma unroll
          for (int c = 0; c < 4; c++) hgb2[(size_t)row * F + c * 16 + l15] = f2bf(cfr[c][i]);
        }
        float ps = cfr[0][i] * as_l[0] + cfr[1][i] * as_l[1] + cfr[2][i] * as_l[2] + cfr[3][i] * as_l[3];
        float pd = cfr[0][i] * ad_l[0] + cfr[1][i] * ad_l[1] + cfr[2][i] * ad_l[2] + cfr[3][i] * ad_l[3];
        #pragma unroll
        for (int o = 1; o <= 8; o <<= 1) { ps += __shfl_xor(ps, o); pd += __shfl_xor(pd, o); }
        if (l15 == 0 && row < n) { als2[row] = ps; ald2[row] = pd; }
      }
    }
  }
}

// ---------------- per-node GAT aggregation from global CSR (self-loop in-register) ----------------
__device__ __forceinline__ void agg_node(int node, int n, const int* __restrict__ offs,
                                         const int* __restrict__ ssrc,
                                         const uint4* __restrict__ hg4,
                                         const float* __restrict__ als,
                                         const float* __restrict__ ald,
                                         float4 bl0, float4 bl1, int l8, float r[8]) {
  int cnode = min(node, n - 1);
  int beg = offs[cnode];
  int deg = offs[cnode + 1] - beg;
  float aldv = ald[cnode];

  float ts = als[cnode] + aldv;
  ts = fmaxf(ts, 0.2f * ts);
  float exs = __expf(ts);
  float s = exs;
  uint4 us = hg4[(size_t)cnode * 8 + l8];
  float acc[8];
  acc[0] = exs * __uint_as_float(us.x << 16);
  acc[1] = exs * __uint_as_float(us.x & 0xffff0000u);
  acc[2] = exs * __uint_as_float(us.y << 16);
  acc[3] = exs * __uint_as_float(us.y & 0xffff0000u);
  acc[4] = exs * __uint_as_float(us.z << 16);
  acc[5] = exs * __uint_as_float(us.z & 0xffff0000u);
  acc[6] = exs * __uint_as_float(us.w << 16);
  acc[7] = exs * __uint_as_float(us.w & 0xffff0000u);

  #pragma unroll 4
  for (int j = 0; j < deg; j++) {
    int src = ssrc[beg + j];
    float t = als[src] + aldv;
    t = fmaxf(t, 0.2f * t);                   // leaky_relu 0.2
    float ex = __expf(t);
    s += ex;
    uint4 u = hg4[(size_t)src * 8 + l8];
    acc[0] = fmaf(ex, __uint_as_float(u.x << 16), acc[0]);
    acc[1] = fmaf(ex, __uint_as_float(u.x & 0xffff0000u), acc[1]);
    acc[2] = fmaf(ex, __uint_as_float(u.y << 16), acc[2]);
    acc[3] = fmaf(ex, __uint_as_float(u.y & 0xffff0000u), acc[3]);
    acc[4] = fmaf(ex, __uint_as_float(u.z << 16), acc[4]);
    acc[5] = fmaf(ex, __uint_as_float(u.z & 0xffff0000u), acc[5]);
    acc[6] = fmaf(ex, __uint_as_float(u.w << 16), acc[6]);
    acc[7] = fmaf(ex, __uint_as_float(u.w & 0xffff0000u), acc[7]);
  }

  float iv = 1.f / (s + 1e-16f);
  r[0] = fmaxf(fmaf(acc[0], iv, bl0.x), 0.f);
  r[1] = fmaxf(fmaf(acc[1], iv, bl0.y), 0.f);
  r[2] = fmaxf(fmaf(acc[2], iv, bl0.z), 0.f);
  r[3] = fmaxf(fmaf(acc[3], iv, bl0.w), 0.f);
  r[4] = fmaxf(fmaf(acc[4], iv, bl1.x), 0.f);
  r[5] = fmaxf(fmaf(acc[5], iv, bl1.y), 0.f);
  r[6] = fmaxf(fmaf(acc[6], iv, bl1.z), 0.f);
  r[7] = fmaxf(fmaf(acc[7], iv, bl1.w), 0.f);
}

// ---------------- layer-2 aggregation + fused readout ----------------
__global__ __launch_bounds__(256) void k_spmm_out(const int* __restrict__ offs, const int* __restrict__ ssrc,
                                                  const unsigned short* __restrict__ hgb,
                                                  const float* __restrict__ als, const float* __restrict__ ald,
                                                  const float* __restrict__ bias, const float* __restrict__ Wout,
                                                  float* __restrict__ out, int n) {
  int tid = threadIdx.x, lane = tid & 63, wv = tid >> 6;
  int g8 = lane >> 3, l8 = lane & 7;
  const uint4* hg4 = (const uint4*)hgb;
  float4 bl0 = ((const float4*)bias)[l8 * 2];
  float4 bl1 = ((const float4*)bias)[l8 * 2 + 1];

  __shared__ float gsl[3];
  if (tid < 3) gsl[tid] = 0.f;

  int node = (blockIdx.x * 4 + wv) * 8 + g8;
  bool nodeok = node < n;
  int cnode = min(node, n - 1);
  float r[8];
  agg_node(node, n, offs, ssrc, hg4, als, ald, bl0, bl1, l8, r);

  int node0 = blockIdx.x * 32;
  int grp0 = node0 / 20;
  int grp = cnode / 20, slot = cnode - grp * 20;
  const float* wr = Wout + slot * F + l8 * 8;
  float dot = 0.f;
  #pragma unroll
  for (int k = 0; k < 8; k++) dot = fmaf(r[k], wr[k], dot);
  #pragma unroll
  for (int o = 1; o <= 4; o <<= 1) dot += __shfl_xor(dot, o);  // within subgroup
  __syncthreads();
  if (nodeok && l8 == 0) atomicAdd(&gsl[grp - grp0], dot);
  __syncthreads();
  if (tid < 3) {
    float v = gsl[tid];
    if (v != 0.f) atomicAdd(out + grp0 + tid, v);
  }
}

// ---------------- launch ----------------
extern "C" void kernel_launch(void* const* d_in, const int* in_sizes, int n_in,
                              void* d_out, int out_size, void* d_ws, size_t ws_size,
                              hipStream_t stream) {
  const float* x   = (const float*)d_in[0];
  const int*   ei  = (const int*)d_in[1];
  const float* W1  = (const float*)d_in[2];
  const float* as1 = (const float*)d_in[3];
  const float* ad1 = (const float*)d_in[4];
  const float* b1  = (const float*)d_in[5];
  const float* W2  = (const float*)d_in[6];
  const float* as2 = (const float*)d_in[7];
  const float* ad2 = (const float*)d_in[8];
  const float* b2  = (const float*)d_in[9];
  const float* Wo  = (const float*)d_in[10];
  const float* bo  = (const float*)d_in[11];
  float* out = (float*)d_out;

  const int N = in_sizes[0] / F;
  const int E = in_sizes[1] / 2;
  const int* esrc = ei;
  const int* edst = ei + E;

  size_t off = 0;
  auto alloc = [&](size_t bytes) -> void* {
    void* p = (char*)d_ws + off;
    off += (bytes + 255) & ~(size_t)255;
    return p;
  };
  unsigned short* hgb  = (unsigned short*)alloc((size_t)N * F * 2);  // layer-1 h (bf16)
  unsigned short* hgb2 = (unsigned short*)alloc((size_t)N * F * 2);  // layer-2 h (bf16)
  float* als  = (float*)alloc((size_t)N * 4);
  float* ald  = (float*)alloc((size_t)N * 4);
  float* als2 = (float*)alloc((size_t)N * 4);
  float* ald2 = (float*)alloc((size_t)N * 4);
  int* offs   = (int*)alloc((size_t)(N + 1) * 4);
  int* bcnt   = (int*)alloc((size_t)1024 * 16 * 4);  // per-bucket counters, 64B-padded
  int* ssrc   = (int*)alloc((size_t)(E + 64) * 4);   // CSR src lists (edges only)
  unsigned int* binned = (unsigned int*)alloc((size_t)1024 * BCAP * 4);
  uint4* wf   = (uint4*)alloc(16384);                // packed W frags: 2 layers x 512 uint4
  (void)ws_size; (void)n_in; (void)out_size;

  const int NG = N / 20;
  const int NB = (N + NPB - 1) / NPB;                // 1024
  const int S = (E + CHMAX - 1) / CHMAX;             // 256 scatter blocks (chunk fits LDS stage)
  const int CH = (((E + S - 1) / S) + 3) & ~3;       // chunk, multiple of 4 for int4 loads

  // W pack + counter zero + out init
  k_prep<<<2, 256, 0, stream>>>(W1, W2, wf, bcnt, NB, out, bo, NG);
  // fused: bucketed scatter w/ LDS sort + coalesced flush (S blocks) + layer-1 GEMM (N/64 blocks)
  k_scatter_gemm1<<<S + (N >> 6), 256, 0, stream>>>(esrc, edst, bcnt, binned, E, CH, S,
                                                    x, wf, as1, ad1, hgb, als, ald, N);
  // fused: per-bucket CSR build + layer-1 aggregation + layer-2 GEMM
  k_csr_g2<<<NB, 256, 0, stream>>>(binned, bcnt, ssrc, offs, hgb, als, ald, b1,
                                   wf + 512, as2, ad2, hgb2, als2, ald2, N, NB);
  // layer-2 aggregation + fused readout
  k_spmm_out<<<(N >> 5), 256, 0, stream>>>(offs, ssrc, hgb2, als2, ald2, b2, Wo, out, N);
}

// Round 11
// 258.479 us; speedup vs baseline: 1.1165x; 1.1165x over previous
//
#include <hip/hip_runtime.h>
#include <math.h>

#define F 64
#define NPB 160        // nodes per csr block
#define CNB 640        // nodes per coarse scatter bucket
#define NBKC 256       // coarse buckets = N/CNB
#define BCAPC 12288    // per-coarse-bucket capacity (mean 10240, +20 sigma)
#define SSTR 3584      // fixed ssrc/stage region per csr block (mean 2560, +20 sigma)

typedef __attribute__((ext_vector_type(8))) short bf16x8;
typedef __attribute__((ext_vector_type(4))) float f32x4;

__device__ inline unsigned short f2bf(float f) {
  unsigned int u = __float_as_uint(f);
  u += 0x7fffu + ((u >> 16) & 1u);   // round-to-nearest-even
  return (unsigned short)(u >> 16);
}

// ---------------- prep: W fragment pack (block 0) + bcnt zero + out init ----------------
__global__ __launch_bounds__(256) void k_prep(const float* __restrict__ W1, const float* __restrict__ W2,
                                              uint4* __restrict__ wf, int* __restrict__ bcnt,
                                              float* __restrict__ out, const float* __restrict__ bo, int ng) {
  int tid = threadIdx.x;
  if (blockIdx.x == 0) {
    // pack W1/W2 into MFMA B-fragment layout: wf[layer*512 + (c*2+kk)*64 + lane] = 8 bf16 (j=0..7)
    for (int i = tid; i < 1024; i += 256) {
      int layer = i >> 9, rem = i & 511;
      int cb = rem >> 6, lane = rem & 63;
      int c = cb >> 1, kk = cb & 1;
      int l15 = lane & 15, quad = lane >> 4;
      const float* W = layer ? W2 : W1;
      unsigned short p[8];
      #pragma unroll
      for (int j = 0; j < 8; j++) {
        int kd = kk * 32 + quad * 8 + j;
        p[j] = f2bf(W[kd * F + c * 16 + l15]);
      }
      wf[i] = *(const uint4*)p;
    }
  } else {
    for (int i = tid; i < NBKC * 16; i += 256) bcnt[i] = 0;  // counters padded to 64B lines
    float b0 = bo[0];
    for (int i = tid; i < ng; i += 256) out[i] = b0;
  }
}

// ---------------- MFMA GEMM body: fp32 input rows -> bf16 h + als/ald ----------------
__device__ __forceinline__ void gemm_body(const float* __restrict__ in, const uint4* __restrict__ wf,
                                          const float* __restrict__ avs, const float* __restrict__ avd,
                                          unsigned short* __restrict__ hgb, float* __restrict__ als,
                                          float* __restrict__ ald, int n, int bid, int nbl) {
  int tid = threadIdx.x, lane = tid & 63, wv = tid >> 6;
  int l15 = lane & 15, quad = lane >> 4;
  bf16x8 bfr[4][2];
  #pragma unroll
  for (int cb = 0; cb < 8; cb++) {
    uint4 u = wf[cb * 64 + lane];
    bfr[cb >> 1][cb & 1] = *(const bf16x8*)&u;
  }
  float as_l[4], ad_l[4];
  #pragma unroll
  for (int c = 0; c < 4; c++) { as_l[c] = avs[c * 16 + l15]; ad_l[c] = avd[c * 16 + l15]; }

  int nchunks = n >> 6;
  for (int chunk = bid; chunk < nchunks; chunk += nbl) {
    int r0 = (chunk << 6) + (wv << 4);
    bf16x8 a0, a1;
    const float4* xr = (const float4*)(in + (size_t)(r0 + l15) * F + quad * 8);
    float4 xa = xr[0], xb = xr[1];
    float4 xc = xr[8], xd = xr[9];
    a0[0] = (short)f2bf(xa.x); a0[1] = (short)f2bf(xa.y); a0[2] = (short)f2bf(xa.z); a0[3] = (short)f2bf(xa.w);
    a0[4] = (short)f2bf(xb.x); a0[5] = (short)f2bf(xb.y); a0[6] = (short)f2bf(xb.z); a0[7] = (short)f2bf(xb.w);
    a1[0] = (short)f2bf(xc.x); a1[1] = (short)f2bf(xc.y); a1[2] = (short)f2bf(xc.z); a1[3] = (short)f2bf(xc.w);
    a1[4] = (short)f2bf(xd.x); a1[5] = (short)f2bf(xd.y); a1[6] = (short)f2bf(xd.z); a1[7] = (short)f2bf(xd.w);
    f32x4 cfr[4];
    #pragma unroll
    for (int c = 0; c < 4; c++) {
      cfr[c] = (f32x4){0.f, 0.f, 0.f, 0.f};
      cfr[c] = __builtin_amdgcn_mfma_f32_16x16x32_bf16(a0, bfr[c][0], cfr[c], 0, 0, 0);
      cfr[c] = __builtin_amdgcn_mfma_f32_16x16x32_bf16(a1, bfr[c][1], cfr[c], 0, 0, 0);
    }
    #pragma unroll
    for (int i = 0; i < 4; i++) {
      int row = r0 + quad * 4 + i;
      #pragma unroll
      for (int c = 0; c < 4; c++) hgb[(size_t)row * F + c * 16 + l15] = f2bf(cfr[c][i]);
      float ps = cfr[0][i] * as_l[0] + cfr[1][i] * as_l[1] + cfr[2][i] * as_l[2] + cfr[3][i] * as_l[3];
      float pd = cfr[0][i] * ad_l[0] + cfr[1][i] * ad_l[1] + cfr[2][i] * ad_l[2] + cfr[3][i] * ad_l[3];
      #pragma unroll
      for (int o = 1; o <= 8; o <<= 1) { ps += __shfl_xor(ps, o); pd += __shfl_xor(pd, o); }
      if (l15 == 0) { als[row] = ps; ald[row] = pd; }
    }
  }
}

// ---------------- fused: coarse-bucketed scatter (blocks < S) + layer-1 GEMM ----------------
// 256 coarse buckets of 640 nodes: run length ~40 entries (160B) -> 64B lines of binned are
// filled by one block in a tight window (minimal fragmentation + eviction re-writes), with 2KB LDS.
// Entry packing: src (bits 0..17) | local (bits 20..29).
__global__ __launch_bounds__(256) void k_scatter_gemm1(const int* __restrict__ esrc, const int* __restrict__ edst,
                                                       int* __restrict__ bcnt, unsigned int* __restrict__ binned,
                                                       int e, int ch, int S,
                                                       const float* __restrict__ x, const uint4* __restrict__ wf,
                                                       const float* __restrict__ avs, const float* __restrict__ avd,
                                                       unsigned short* __restrict__ hgb, float* __restrict__ als,
                                                       float* __restrict__ ald, int n) {
  int k = blockIdx.x, tid = threadIdx.x;
  if (k < S) {
    __shared__ int hist[NBKC];
    __shared__ int cur[NBKC];
    if (tid < NBKC) hist[tid] = 0;
    __syncthreads();
    int beg = k * ch, end = min(e, beg + ch);
    int len = end - beg;
    if (len <= 0) return;
    int nv = len >> 2;  // beg is 16B-aligned (ch multiple of 4)
    // phase A: histogram (int4)
    for (int g = tid; g < nv; g += 256) {
      int4 d4 = *(const int4*)(edst + beg + (g << 2));
      atomicAdd(&hist[d4.x / CNB], 1);
      atomicAdd(&hist[d4.y / CNB], 1);
      atomicAdd(&hist[d4.z / CNB], 1);
      atomicAdd(&hist[d4.w / CNB], 1);
    }
    for (int i = beg + (nv << 2) + tid; i < end; i += 256) atomicAdd(&hist[edst[i] / CNB], 1);
    __syncthreads();
    // phase B: reserve per-bucket runs (one global atomic per (block,bucket))
    if (tid < NBKC) {
      int c = hist[tid];
      int base = 0;
      if (c) base = atomicAdd(&bcnt[tid * 16], c);
      cur[tid] = tid * BCAPC + base;
    }
    __syncthreads();
    // phase C: place
    for (int g = tid; g < nv; g += 256) {
      int i = beg + (g << 2);
      int4 d4 = *(const int4*)(edst + i);
      int4 s4 = *(const int4*)(esrc + i);
      #pragma unroll
      for (int j = 0; j < 4; j++) {
        int d = (j == 0) ? d4.x : (j == 1) ? d4.y : (j == 2) ? d4.z : d4.w;
        int s = (j == 0) ? s4.x : (j == 1) ? s4.y : (j == 2) ? s4.z : s4.w;
        int b = d / CNB;
        int p = atomicAdd(&cur[b], 1);
        if (p < (b + 1) * BCAPC) binned[p] = (unsigned int)s | ((unsigned int)(d - b * CNB) << 20);
      }
    }
    for (int i = beg + (nv << 2) + tid; i < end; i += 256) {
      int d = edst[i];
      int b = d / CNB;
      int p = atomicAdd(&cur[b], 1);
      if (p < (b + 1) * BCAPC) binned[p] = (unsigned int)esrc[i] | ((unsigned int)(d - b * CNB) << 20);
    }
    return;
  }
  gemm_body(x, wf, avs, avd, hgb, als, ald, n, k - S, (int)gridDim.x - S);
}

// ---------------- fused: per-block CSR build (filtered from coarse bucket) + layer-1 agg + layer-2 GEMM ----
// Block g handles nodes [g*160, g*160+160) = quarter `part` of coarse bucket g>>2. Reads the
// coarse run, filters by local range, sorts into its fixed SSTR region. ndeg[] carries degree
// (capped so all reads stay in-bounds); offs[] carries per-node base.
__global__ __launch_bounds__(256) void k_csr_g2(const unsigned int* __restrict__ binned,
                                                const int* __restrict__ bcnt,
                                                int* __restrict__ ssrc, int* __restrict__ offs,
                                                int* __restrict__ ndeg,
                                                const unsigned short* __restrict__ hgb,
                                                const float* __restrict__ als, const float* __restrict__ ald,
                                                const float* __restrict__ bias, const uint4* __restrict__ wf2,
                                                const float* __restrict__ avs, const float* __restrict__ avd,
                                                unsigned short* __restrict__ hgb2, float* __restrict__ als2,
                                                float* __restrict__ ald2, int n) {
  __shared__ int ncnt[NPB];
  __shared__ int noff[NPB];
  __shared__ int cur[NPB];
  __shared__ int wsum[4];
  __shared__ int btot_sh;
  __shared__ int stage[SSTR];
  __shared__ __align__(16) unsigned short hsh[NPB][72];  // stride 144B: 16B-aligned rows, 2-way banks
  int g = blockIdx.x, tid = threadIdx.x;
  int lane = tid & 63, wv = tid >> 6;
  int cb = g >> 2;
  unsigned int lo = (unsigned int)((g & 3) * NPB);
  int ec = min(bcnt[cb * 16], BCAPC);
  int node0 = g * NPB;
  int nn = min(NPB, n - node0);
  const uint4* bq = (const uint4*)(binned + (size_t)cb * BCAPC);  // BCAPC%4==0 -> 16B aligned
  int nv4 = ec >> 2;
  if (tid < NPB) ncnt[tid] = 0;
  __syncthreads();
  // hist pass (uint4, filtered by local range)
  for (int i = tid; i < nv4; i += 256) {
    uint4 q = bq[i];
    unsigned int l0 = (q.x >> 20) - lo; if (l0 < NPB) atomicAdd(&ncnt[l0], 1);
    unsigned int l1 = (q.y >> 20) - lo; if (l1 < NPB) atomicAdd(&ncnt[l1], 1);
    unsigned int l2 = (q.z >> 20) - lo; if (l2 < NPB) atomicAdd(&ncnt[l2], 1);
    unsigned int l3 = (q.w >> 20) - lo; if (l3 < NPB) atomicAdd(&ncnt[l3], 1);
  }
  for (int i = (nv4 << 2) + tid; i < ec; i += 256) {
    unsigned int l0 = (binned[(size_t)cb * BCAPC + i] >> 20) - lo;
    if (l0 < NPB) atomicAdd(&ncnt[l0], 1);
  }
  __syncthreads();
  // exclusive scan over nn node counts: wave shfl scan + cross-wave fixup
  int v = (tid < nn) ? ncnt[tid] : 0;
  int x = v;
  #pragma unroll
  for (int o = 1; o <= 32; o <<= 1) { int y = __shfl_up(x, o); if (lane >= o) x += y; }
  if (lane == 63) wsum[wv] = x;
  __syncthreads();
  int add = 0;
  for (int w = 0; w < wv; w++) add += wsum[w];
  int incl = x + add;
  if (tid < nn) {
    int nf = incl - v;
    int capdeg = max(0, min(v, SSTR - nf));   // guarantee reads stay inside [g*SSTR, g*SSTR+SSTR)
    noff[tid] = nf;
    cur[tid] = nf;
    ncnt[tid] = capdeg;                        // agg reads capped degree
    offs[node0 + tid] = g * SSTR + nf;
    ndeg[node0 + tid] = capdeg;
    if (tid == nn - 1) btot_sh = min(incl, SSTR);
  }
  __syncthreads();
  // sort pass (uint4, filtered) -> stage
  for (int i = tid; i < nv4; i += 256) {
    uint4 q = bq[i];
    unsigned int l0 = (q.x >> 20) - lo; if (l0 < NPB) { int p = atomicAdd(&cur[l0], 1); if (p < SSTR) stage[p] = (int)(q.x & 0xFFFFFu); }
    unsigned int l1 = (q.y >> 20) - lo; if (l1 < NPB) { int p = atomicAdd(&cur[l1], 1); if (p < SSTR) stage[p] = (int)(q.y & 0xFFFFFu); }
    unsigned int l2 = (q.z >> 20) - lo; if (l2 < NPB) { int p = atomicAdd(&cur[l2], 1); if (p < SSTR) stage[p] = (int)(q.z & 0xFFFFFu); }
    unsigned int l3 = (q.w >> 20) - lo; if (l3 < NPB) { int p = atomicAdd(&cur[l3], 1); if (p < SSTR) stage[p] = (int)(q.w & 0xFFFFFu); }
  }
  for (int i = (nv4 << 2) + tid; i < ec; i += 256) {
    unsigned int q = binned[(size_t)cb * BCAPC + i];
    unsigned int l0 = (q >> 20) - lo;
    if (l0 < NPB) { int p = atomicAdd(&cur[l0], 1); if (p < SSTR) stage[p] = (int)(q & 0xFFFFFu); }
  }
  __syncthreads();
  // persist CSR for spmm_out (coalesced; overlaps with agg below across blocks)
  int btot = btot_sh;
  for (int i = tid; i < btot; i += 256) ssrc[(size_t)g * SSTR + i] = stage[i];

  // ---- layer-1 aggregation for this block's nodes, edge ids from LDS ----
  int g8 = lane >> 3, l8 = lane & 7;
  const uint4* hg4 = (const uint4*)hgb;
  float4 bl0 = ((const float4*)bias)[l8 * 2];
  float4 bl1 = ((const float4*)bias)[l8 * 2 + 1];

  for (int p = 0; p < 5; p++) {
    int row = p * 32 + wv * 8 + g8;       // 0..159
    int node = node0 + row;
    bool rowok = row < nn;
    int cnode = min(node, n - 1);
    int deg = rowok ? ncnt[row] : 0;
    int lbeg = rowok ? noff[row] : 0;
    float aldv = ald[cnode];

    // self-loop term
    float ts = als[cnode] + aldv;
    ts = fmaxf(ts, 0.2f * ts);
    float exs = __expf(ts);
    float s = exs;
    uint4 us = hg4[(size_t)cnode * 8 + l8];
    float acc8[8];
    acc8[0] = exs * __uint_as_float(us.x << 16);
    acc8[1] = exs * __uint_as_float(us.x & 0xffff0000u);
    acc8[2] = exs * __uint_as_float(us.y << 16);
    acc8[3] = exs * __uint_as_float(us.y & 0xffff0000u);
    acc8[4] = exs * __uint_as_float(us.z << 16);
    acc8[5] = exs * __uint_as_float(us.z & 0xffff0000u);
    acc8[6] = exs * __uint_as_float(us.w << 16);
    acc8[7] = exs * __uint_as_float(us.w & 0xffff0000u);

    #pragma unroll 4
    for (int j = 0; j < deg; j++) {
      int src = stage[lbeg + j];
      float t = als[src] + aldv;
      t = fmaxf(t, 0.2f * t);               // leaky_relu 0.2
      float ex = __expf(t);
      s += ex;
      uint4 u = hg4[(size_t)src * 8 + l8];
      acc8[0] = fmaf(ex, __uint_as_float(u.x << 16), acc8[0]);
      acc8[1] = fmaf(ex, __uint_as_float(u.x & 0xffff0000u), acc8[1]);
      acc8[2] = fmaf(ex, __uint_as_float(u.y << 16), acc8[2]);
      acc8[3] = fmaf(ex, __uint_as_float(u.y & 0xffff0000u), acc8[3]);
      acc8[4] = fmaf(ex, __uint_as_float(u.z << 16), acc8[4]);
      acc8[5] = fmaf(ex, __uint_as_float(u.z & 0xffff0000u), acc8[5]);
      acc8[6] = fmaf(ex, __uint_as_float(u.w << 16), acc8[6]);
      acc8[7] = fmaf(ex, __uint_as_float(u.w & 0xffff0000u), acc8[7]);
    }

    float iv = 1.f / (s + 1e-16f);
    float r[8];
    r[0] = fmaxf(fmaf(acc8[0], iv, bl0.x), 0.f);
    r[1] = fmaxf(fmaf(acc8[1], iv, bl0.y), 0.f);
    r[2] = fmaxf(fmaf(acc8[2], iv, bl0.z), 0.f);
    r[3] = fmaxf(fmaf(acc8[3], iv, bl0.w), 0.f);
    r[4] = fmaxf(fmaf(acc8[4], iv, bl1.x), 0.f);
    r[5] = fmaxf(fmaf(acc8[5], iv, bl1.y), 0.f);
    r[6] = fmaxf(fmaf(acc8[6], iv, bl1.z), 0.f);
    r[7] = fmaxf(fmaf(acc8[7], iv, bl1.w), 0.f);
    unsigned short pk[8];
    #pragma unroll
    for (int kk = 0; kk < 8; kk++) pk[kk] = f2bf(r[kk]);
    *(uint4*)&hsh[row][l8 * 8] = *(const uint4*)pk;
  }
  __syncthreads();

  // ---- layer-2 GEMM on 10 strips of 16 rows ----
  int l15 = lane & 15, quad = lane >> 4;
  bf16x8 bfr[4][2];
  #pragma unroll
  for (int cb2 = 0; cb2 < 8; cb2++) {
    uint4 u = wf2[cb2 * 64 + lane];
    bfr[cb2 >> 1][cb2 & 1] = *(const bf16x8*)&u;
  }
  float as_l[4], ad_l[4];
  #pragma unroll
  for (int c = 0; c < 4; c++) { as_l[c] = avs[c * 16 + l15]; ad_l[c] = avd[c * 16 + l15]; }

  #pragma unroll
  for (int t = 0; t < 3; t++) {
    int strip = t * 4 + wv;
    if (strip < 10) {
      int r0 = strip << 4;
      uint4 u0 = *(const uint4*)&hsh[r0 + l15][quad * 8];
      uint4 u1 = *(const uint4*)&hsh[r0 + l15][quad * 8 + 32];
      bf16x8 a0 = *(const bf16x8*)&u0;
      bf16x8 a1 = *(const bf16x8*)&u1;
      f32x4 cfr[4];
      #pragma unroll
      for (int c = 0; c < 4; c++) {
        cfr[c] = (f32x4){0.f, 0.f, 0.f, 0.f};
        cfr[c] = __builtin_amdgcn_mfma_f32_16x16x32_bf16(a0, bfr[c][0], cfr[c], 0, 0, 0);
        cfr[c] = __builtin_amdgcn_mfma_f32_16x16x32_bf16(a1, bfr[c][1], cfr[c], 0, 0, 0);
      }
      #pragma unroll
      for (int i = 0; i < 4; i++) {
        int row = node0 + r0 + quad * 4 + i;
        if (row < n) {
          #pragma unroll
          for (int c = 0; c < 4; c++) hgb2[(size_t)row * F + c * 16 + l15] = f2bf(cfr[c][i]);
        }
        float ps = cfr[0][i] * as_l[0] + cfr[1][i] * as_l[1] + cfr[2][i] * as_l[2] + cfr[3][i] * as_l[3];
        float pd = cfr[0][i] * ad_l[0] + cfr[1][i] * ad_l[1] + cfr[2][i] * ad_l[2] + cfr[3][i] * ad_l[3];
        #pragma unroll
        for (int o = 1; o <= 8; o <<= 1) { ps += __shfl_xor(ps, o); pd += __shfl_xor(pd, o); }
        if (l15 == 0 && row < n) { als2[row] = ps; ald2[row] = pd; }
      }
    }
  }
}

// ---------------- per-node GAT aggregation from global CSR (self-loop in-register) ----------------
__device__ __forceinline__ void agg_node(int node, int n, const int* __restrict__ offs,
                                         const int* __restrict__ ndeg,
                                         const int* __restrict__ ssrc,
                                         const uint4* __restrict__ hg4,
                                         const float* __restrict__ als,
                                         const float* __restrict__ ald,
                                         float4 bl0, float4 bl1, int l8, float r[8]) {
  int cnode = min(node, n - 1);
  int beg = offs[cnode];
  int deg = ndeg[cnode];
  float aldv = ald[cnode];

  float ts = als[cnode] + aldv;
  ts = fmaxf(ts, 0.2f * ts);
  float exs = __expf(ts);
  float s = exs;
  uint4 us = hg4[(size_t)cnode * 8 + l8];
  float acc[8];
  acc[0] = exs * __uint_as_float(us.x << 16);
  acc[1] = exs * __uint_as_float(us.x & 0xffff0000u);
  acc[2] = exs * __uint_as_float(us.y << 16);
  acc[3] = exs * __uint_as_float(us.y & 0xffff0000u);
  acc[4] = exs * __uint_as_float(us.z << 16);
  acc[5] = exs * __uint_as_float(us.z & 0xffff0000u);
  acc[6] = exs * __uint_as_float(us.w << 16);
  acc[7] = exs * __uint_as_float(us.w & 0xffff0000u);

  #pragma unroll 4
  for (int j = 0; j < deg; j++) {
    int src = ssrc[beg + j];
    float t = als[src] + aldv;
    t = fmaxf(t, 0.2f * t);                   // leaky_relu 0.2
    float ex = __expf(t);
    s += ex;
    uint4 u = hg4[(size_t)src * 8 + l8];
    acc[0] = fmaf(ex, __uint_as_float(u.x << 16), acc[0]);
    acc[1] = fmaf(ex, __uint_as_float(u.x & 0xffff0000u), acc[1]);
    acc[2] = fmaf(ex, __uint_as_float(u.y << 16), acc[2]);
    acc[3] = fmaf(ex, __uint_as_float(u.y & 0xffff0000u), acc[3]);
    acc[4] = fmaf(ex, __uint_as_float(u.z << 16), acc[4]);
    acc[5] = fmaf(ex, __uint_as_float(u.z & 0xffff0000u), acc[5]);
    acc[6] = fmaf(ex, __uint_as_float(u.w << 16), acc[6]);
    acc[7] = fmaf(ex, __uint_as_float(u.w & 0xffff0000u), acc[7]);
  }

  float iv = 1.f / (s + 1e-16f);
  r[0] = fmaxf(fmaf(acc[0], iv, bl0.x), 0.f);
  r[1] = fmaxf(fmaf(acc[1], iv, bl0.y), 0.f);
  r[2] = fmaxf(fmaf(acc[2], iv, bl0.z), 0.f);
  r[3] = fmaxf(fmaf(acc[3], iv, bl0.w), 0.f);
  r[4] = fmaxf(fmaf(acc[4], iv, bl1.x), 0.f);
  r[5] = fmaxf(fmaf(acc[5], iv, bl1.y), 0.f);
  r[6] = fmaxf(fmaf(acc[6], iv, bl1.z), 0.f);
  r[7] = fmaxf(fmaf(acc[7], iv, bl1.w), 0.f);
}

// ---------------- layer-2 aggregation + fused readout ----------------
__global__ __launch_bounds__(256) void k_spmm_out(const int* __restrict__ offs, const int* __restrict__ ndeg,
                                                  const int* __restrict__ ssrc,
                                                  const unsigned short* __restrict__ hgb,
                                                  const float* __restrict__ als, const float* __restrict__ ald,
                                                  const float* __restrict__ bias, const float* __restrict__ Wout,
                                                  float* __restrict__ out, int n) {
  int tid = threadIdx.x, lane = tid & 63, wv = tid >> 6;
  int g8 = lane >> 3, l8 = lane & 7;
  const uint4* hg4 = (const uint4*)hgb;
  float4 bl0 = ((const float4*)bias)[l8 * 2];
  float4 bl1 = ((const float4*)bias)[l8 * 2 + 1];

  __shared__ float gsl[3];
  if (tid < 3) gsl[tid] = 0.f;

  int node = (blockIdx.x * 4 + wv) * 8 + g8;
  bool nodeok = node < n;
  int cnode = min(node, n - 1);
  float r[8];
  agg_node(node, n, offs, ndeg, ssrc, hg4, als, ald, bl0, bl1, l8, r);

  int node0 = blockIdx.x * 32;
  int grp0 = node0 / 20;
  int grp = cnode / 20, slot = cnode - grp * 20;
  const float* wr = Wout + slot * F + l8 * 8;
  float dot = 0.f;
  #pragma unroll
  for (int k = 0; k < 8; k++) dot = fmaf(r[k], wr[k], dot);
  #pragma unroll
  for (int o = 1; o <= 4; o <<= 1) dot += __shfl_xor(dot, o);  // within subgroup
  __syncthreads();
  if (nodeok && l8 == 0) atomicAdd(&gsl[grp - grp0], dot);
  __syncthreads();
  if (tid < 3) {
    float v = gsl[tid];
    if (v != 0.f) atomicAdd(out + grp0 + tid, v);
  }
}

// ---------------- launch ----------------
extern "C" void kernel_launch(void* const* d_in, const int* in_sizes, int n_in,
                              void* d_out, int out_size, void* d_ws, size_t ws_size,
                              hipStream_t stream) {
  const float* x   = (const float*)d_in[0];
  const int*   ei  = (const int*)d_in[1];
  const float* W1  = (const float*)d_in[2];
  const float* as1 = (const float*)d_in[3];
  const float* ad1 = (const float*)d_in[4];
  const float* b1  = (const float*)d_in[5];
  const float* W2  = (const float*)d_in[6];
  const float* as2 = (const float*)d_in[7];
  const float* ad2 = (const float*)d_in[8];
  const float* b2  = (const float*)d_in[9];
  const float* Wo  = (const float*)d_in[10];
  const float* bo  = (const float*)d_in[11];
  float* out = (float*)d_out;

  const int N = in_sizes[0] / F;
  const int E = in_sizes[1] / 2;
  const int* esrc = ei;
  const int* edst = ei + E;

  size_t off = 0;
  auto alloc = [&](size_t bytes) -> void* {
    void* p = (char*)d_ws + off;
    off += (bytes + 255) & ~(size_t)255;
    return p;
  };
  unsigned short* hgb  = (unsigned short*)alloc((size_t)N * F * 2);  // layer-1 h (bf16)
  unsigned short* hgb2 = (unsigned short*)alloc((size_t)N * F * 2);  // layer-2 h (bf16)
  float* als  = (float*)alloc((size_t)N * 4);
  float* ald  = (float*)alloc((size_t)N * 4);
  float* als2 = (float*)alloc((size_t)N * 4);
  float* ald2 = (float*)alloc((size_t)N * 4);
  int* offs   = (int*)alloc((size_t)(N + 1) * 4);
  int* ndeg   = (int*)alloc((size_t)N * 4);
  int* bcnt   = (int*)alloc((size_t)NBKC * 16 * 4);  // per-coarse-bucket counters, 64B-padded
  int* ssrc   = (int*)alloc((size_t)1024 * SSTR * 4);  // fixed-stride CSR regions (14.7MB)
  unsigned int* binned = (unsigned int*)alloc((size_t)NBKC * BCAPC * 4);  // 12.6MB
  uint4* wf   = (uint4*)alloc(16384);                // packed W frags: 2 layers x 512 uint4
  (void)ws_size; (void)n_in; (void)out_size;

  const int NG = N / 20;
  const int NBLK = (N + NPB - 1) / NPB;              // 1024 csr blocks
  const int S = 256;                                 // scatter blocks
  const int CH = (((E + S - 1) / S) + 3) & ~3;       // chunk, multiple of 4 for int4 loads

  // W pack + counter zero + out init
  k_prep<<<2, 256, 0, stream>>>(W1, W2, wf, bcnt, out, bo, NG);
  // fused: coarse-bucketed scatter (S blocks) + layer-1 GEMM (N/64 blocks)
  k_scatter_gemm1<<<S + (N >> 6), 256, 0, stream>>>(esrc, edst, bcnt, binned, E, CH, S,
                                                    x, wf, as1, ad1, hgb, als, ald, N);
  // fused: per-block CSR build (filtered) + layer-1 aggregation + layer-2 GEMM
  k_csr_g2<<<NBLK, 256, 0, stream>>>(binned, bcnt, ssrc, offs, ndeg, hgb, als, ald, b1,
                                     wf + 512, as2, ad2, hgb2, als2, ald2, N);
  // layer-2 aggregation + fused readout
  k_spmm_out<<<(N >> 5), 256, 0, stream>>>(offs, ndeg, ssrc, hgb2, als2, ald2, b2, Wo, out, N);
}